// Round 6
// baseline (321.931 us; speedup 1.0000x reference)
//
#include <hip/hip_runtime.h>
#include <hip/hip_bf16.h>
#include <math.h>

#define B 1024
#define D 512
#define KC 100000
#define MARGIN 0.3f
#define EPSSM 0.1f
#define NPANEL 391   // ceil(KC/256)

typedef __attribute__((ext_vector_type(8))) short bf16x8;
typedef __attribute__((ext_vector_type(4))) float f32x4;

__device__ __forceinline__ unsigned cvtpk(float lo, float hi) {
    union { __hip_bfloat162 h2; unsigned u; } cv;
    cv.h2 = __float22bfloat162_rn(make_float2(lo, hi));
    return cv.u;
}

__device__ __forceinline__ void async16(const void* g, void* l) {
    __builtin_amdgcn_global_load_lds((const __attribute__((address_space(1))) unsigned int*)g,
                                     (__attribute__((address_space(3))) unsigned int*)l,
                                     16, 0, 0);
}

#define VMCNT(n) asm volatile("s_waitcnt vmcnt(" #n ")" ::: "memory")
#define FENCE    asm volatile("" ::: "memory")

// ---------------- init workspace ----------------
__global__ void init_ws(float* ws) {
    int i = blockIdx.x * blockDim.x + threadIdx.x;
    if (i < 2 * B) ws[i] = 0.f;   // sumexp[B], sumlogit[B]
}

// ---------------- pack x -> bf16 LDS-image tiles ----------------
// Region (rblk 0..3, u 0..7, half 0..1) = 8192 ushorts (16KB) = [128 rows][8 k-units]
// data unit (rloc, ku) stored at position rloc*8 + (ku ^ (rloc&7)).
__global__ __launch_bounds__(256) void pack_x(const float* __restrict__ x,
                                              unsigned short* __restrict__ xp) {
    int gid = blockIdx.x * 256 + threadIdx.x;   // 1024*64 = 65536
    int row = gid >> 6;
    int rest = gid & 63;
    int u = rest >> 3, ku = rest & 7;
    int rblk = row >> 8, h = (row >> 7) & 1, rloc = row & 127;
    const float* src = x + (size_t)row * D + u * 64 + ku * 8;
    float4 a = *(const float4*)src;
    float4 b2 = *(const float4*)(src + 4);
    unsigned pv[4] = { cvtpk(a.x, a.y), cvtpk(a.z, a.w), cvtpk(b2.x, b2.y), cvtpk(b2.z, b2.w) };
    size_t off = ((size_t)((rblk * 8 + u) * 2 + h) << 13) + (size_t)(rloc * 8 + (ku ^ (rloc & 7))) * 8;
    *(uint4*)(xp + off) = *(uint4*)pv;
}

// ---------------- pack W -> bf16 LDS-image tiles ----------------
// Region (panel, u 0..7, kh 0..1) = 8192 ushorts = [256 rows][4 k-units]
// data unit (prow, u2) stored at position prow*4 + (u2 ^ ((prow>>1)&3)).
__global__ __launch_bounds__(256) void pack_w(const float* __restrict__ W,
                                              unsigned short* __restrict__ wp) {
    size_t gid = (size_t)blockIdx.x * 256 + threadIdx.x;   // KC*64 = 6.4e6
    int c = (int)(gid >> 6);
    int rest = (int)(gid & 63);
    int u = rest >> 3, kh = (rest >> 2) & 1, u2 = rest & 3;
    const float* src = W + (size_t)c * D + u * 64 + kh * 32 + u2 * 8;
    float4 a = *(const float4*)src;
    float4 b2 = *(const float4*)(src + 4);
    unsigned pv[4] = { cvtpk(a.x, a.y), cvtpk(a.z, a.w), cvtpk(b2.x, b2.y), cvtpk(b2.z, b2.w) };
    int panel = c >> 8, prow = c & 255;
    size_t off = ((size_t)((panel * 8 + u) * 2 + kh) << 13) + (size_t)(prow * 4 + (u2 ^ ((prow >> 1) & 3))) * 8;
    *(uint4*)(wp + off) = *(uint4*)pv;
}

// ---------------- triplet: batch-hard per 8 rows (fp32, small) ----------------
__global__ __launch_bounds__(256) void triplet_kernel(const float* __restrict__ x,
                                                      const int* __restrict__ labels,
                                                      float* __restrict__ tw) {
    const int tid = threadIdx.x;
    const int row0 = blockIdx.x * 8;
    __shared__ float xs[8][D];
    __shared__ int labs[8];
    __shared__ float sqi[8];
    __shared__ float red_ap[8][4], red_an[8][4];

    for (int f = tid; f < 8 * (D / 4); f += 256) {
        int r = f / (D / 4);
        int p = f % (D / 4);
        *(float4*)&xs[r][p * 4] = *(const float4*)&x[(size_t)(row0 + r) * D + p * 4];
    }
    if (tid < 8) labs[tid] = labels[row0 + tid];
    __syncthreads();
    if (tid < 8) {
        float s = 0.f;
        for (int k = 0; k < D; ++k) s += xs[tid][k] * xs[tid][k];
        sqi[tid] = s;
    }
    __syncthreads();

    float ap[8], an[8];
#pragma unroll
    for (int r = 0; r < 8; ++r) { ap[r] = -INFINITY; an[r] = INFINITY; }

    for (int j = tid; j < B; j += 256) {
        int labj = labels[j];
        float dot[8];
        float sqj = 0.f;
#pragma unroll
        for (int r = 0; r < 8; ++r) dot[r] = 0.f;
        for (int kc = 0; kc < D; kc += 32) {
            float4 xj[8];
#pragma unroll
            for (int u = 0; u < 8; ++u) xj[u] = *(const float4*)&x[(size_t)j * D + kc + u * 4];
#pragma unroll
            for (int u = 0; u < 8; ++u)
                sqj += xj[u].x * xj[u].x + xj[u].y * xj[u].y + xj[u].z * xj[u].z + xj[u].w * xj[u].w;
#pragma unroll
            for (int r = 0; r < 8; ++r) {
                float d = 0.f;
#pragma unroll
                for (int u = 0; u < 8; ++u) {
                    const float4 a = *(const float4*)&xs[r][kc + u * 4];
                    d += a.x * xj[u].x + a.y * xj[u].y + a.z * xj[u].z + a.w * xj[u].w;
                }
                dot[r] += d;
            }
        }
#pragma unroll
        for (int r = 0; r < 8; ++r) {
            float d2 = sqi[r] + sqj - 2.f * dot[r];
            float dist = sqrtf(fmaxf(d2, 1e-12f));
            if (labj == labs[r]) ap[r] = fmaxf(ap[r], dist);
            else an[r] = fminf(an[r], dist);
        }
    }
#pragma unroll
    for (int r = 0; r < 8; ++r) {
        for (int o = 32; o >= 1; o >>= 1) {
            ap[r] = fmaxf(ap[r], __shfl_xor(ap[r], o));
            an[r] = fminf(an[r], __shfl_xor(an[r], o));
        }
    }
    int wid = tid >> 6;
    if ((tid & 63) == 0) {
#pragma unroll
        for (int r = 0; r < 8; ++r) { red_ap[r][wid] = ap[r]; red_an[r][wid] = an[r]; }
    }
    __syncthreads();
    if (tid < 8) {
        float a = -INFINITY, n = INFINITY;
#pragma unroll
        for (int w = 0; w < 4; ++w) { a = fmaxf(a, red_ap[tid][w]); n = fminf(n, red_an[tid][w]); }
        tw[row0 + tid] = fmaxf(a - n + MARGIN, 0.f);
    }
}

// ---------------- label logit: t[i] = x_i . W[label_i] + b[label_i] (exact fp32) ---
__global__ __launch_bounds__(256) void tlabel_kernel(const float* __restrict__ x,
                                                     const float* __restrict__ W,
                                                     const float* __restrict__ bias,
                                                     const int* __restrict__ labels,
                                                     float* __restrict__ t) {
    int wid = threadIdx.x >> 6, lane = threadIdx.x & 63;
    int row = blockIdx.x * 4 + wid;
    int lab = labels[row];
    const float* xr = x + (size_t)row * D;
    const float* wr = W + (size_t)lab * D;
    float dsum = 0.f;
#pragma unroll
    for (int u = 0; u < 2; ++u) {
        int k = (lane * 2 + u) * 4;
        float4 a = *(const float4*)&xr[k];
        float4 w = *(const float4*)&wr[k];
        dsum += a.x * w.x + a.y * w.y + a.z * w.z + a.w * w.w;
    }
    for (int o = 32; o >= 1; o >>= 1) dsum += __shfl_xor(dsum, o);
    if (lane == 0) t[row] = dsum + bias[lab];
}

// ============ 8-phase 256x256xBK64 bf16 MFMA GEMM (T2+T3+T4+T5) ============
// 512 thr (8 waves, 2M x 4N; wave tile 128x64). LDS = 8 half-slots x 16KB = 128KB:
// slots [parity][A0,A1,Bk0,Bk1]. Per K-tile: 4 phases {ds_read subtile; stage one
// half-tile (2 gload_lds); counted vmcnt; barrier; 16 MFMA @setprio; barrier}.
// Swizzle baked into pack layout -> linear gload_lds + conflict-free ds_read_b128.
__global__ __launch_bounds__(512, 2) void ce_gemm_p(const unsigned short* __restrict__ xp,
                                                    const unsigned short* __restrict__ wp,
                                                    const float* __restrict__ bias,
                                                    float* __restrict__ sumexp,
                                                    float* __restrict__ sumlogit) {
    const int b = blockIdx.x;
    const int xcd = b & 7, slot = b >> 3;
    const int c = (slot >> 2) * 8 + xcd;   // 4 row-blocks of one panel share an XCD
    const int r = slot & 3;
    if (c >= NPANEL) return;
    const int rowbase = r * 256;
    const int cbase = c * 256;

    extern __shared__ unsigned short lds[];   // 65536 ushorts = 128KB

    const int tid = threadIdx.x;
    const int lane = tid & 63;
    const int wid = tid >> 6;
    const int wm = wid >> 2, wn = wid & 3;
    const int q = lane >> 4, l15 = lane & 15;

    f32x4 acc[8][4];
#pragma unroll
    for (int m = 0; m < 8; ++m)
#pragma unroll
        for (int n = 0; n < 4; ++n) acc[m][n] = (f32x4){0.f, 0.f, 0.f, 0.f};

#define STAGE_A(u_, h_) {                                                          \
        const unsigned short* g = xp + ((size_t)((r * 8 + (u_)) * 2 + (h_)) << 13);\
        unsigned short* l = &lds[((((u_) & 1) * 4 + (h_)) << 13)];                 \
        async16(g + tid * 8, l + tid * 8);                                         \
        async16(g + 4096 + tid * 8, l + 4096 + tid * 8); }
#define STAGE_B(u_, h_) {                                                          \
        const unsigned short* g = wp + ((size_t)((c * 8 + (u_)) * 2 + (h_)) << 13);\
        unsigned short* l = &lds[((((u_) & 1) * 4 + 2 + (h_)) << 13)];             \
        async16(g + tid * 8, l + tid * 8);                                         \
        async16(g + 4096 + tid * 8, l + 4096 + tid * 8); }
#define READ_A(mg_, ks_) {                                                         \
        const unsigned short* sA = &lds[(((u & 1) * 4 + wm) << 13)];               \
        _Pragma("unroll") for (int mf = 0; mf < 4; ++mf) {                         \
            int rloc = ((mg_) * 4 + mf) * 16 + l15;                                \
            int unit = rloc * 8 + (((ks_) * 4 + q) ^ (rloc & 7));                  \
            af[mf] = *(const bf16x8*)&sA[unit * 8]; } }
#define READ_B(ks_) {                                                              \
        const unsigned short* sB = &lds[(((u & 1) * 4 + 2 + (ks_)) << 13)];        \
        _Pragma("unroll") for (int nf = 0; nf < 4; ++nf) {                         \
            int row = wn * 64 + nf * 16 + l15;                                     \
            int unit = row * 4 + (q ^ ((row >> 1) & 3));                           \
            bfr[nf] = *(const bf16x8*)&sB[unit * 8]; } }
#define MFMAC(mg_) {                                                               \
        __builtin_amdgcn_s_setprio(1);                                             \
        _Pragma("unroll") for (int mf = 0; mf < 4; ++mf)                           \
        _Pragma("unroll") for (int nf = 0; nf < 4; ++nf)                           \
            acc[(mg_) * 4 + mf][nf] = __builtin_amdgcn_mfma_f32_16x16x32_bf16(     \
                af[mf], bfr[nf], acc[(mg_) * 4 + mf][nf], 0, 0, 0);                \
        __builtin_amdgcn_s_setprio(0); }

    // prologue: tile 0 fully staged; keep Bk1(0)'s 2 loads in flight
    STAGE_A(0, 0); STAGE_A(0, 1); STAGE_B(0, 0);
    STAGE_B(0, 1);
    VMCNT(2);
    __builtin_amdgcn_s_barrier(); FENCE;

    bf16x8 af[4], bfr[4];
#pragma unroll
    for (int u = 0; u < 8; ++u) {
        // ---- ph0: (ks0, mg0) ----
        READ_A(0, 0); READ_B(0);
        if (u < 7) STAGE_A(u + 1, 0);
        __builtin_amdgcn_s_barrier(); FENCE;
        MFMAC(0);
        __builtin_amdgcn_s_barrier(); FENCE;
        // ---- ph1: (ks0, mg1) ----
        READ_A(1, 0);
        if (u < 7) { STAGE_A(u + 1, 1); VMCNT(4); } else { VMCNT(0); }
        __builtin_amdgcn_s_barrier(); FENCE;
        MFMAC(1);
        __builtin_amdgcn_s_barrier(); FENCE;
        // ---- ph2: (ks1, mg0) ----
        READ_A(0, 1); READ_B(1);
        if (u < 7) STAGE_B(u + 1, 0);
        __builtin_amdgcn_s_barrier(); FENCE;
        MFMAC(0);
        __builtin_amdgcn_s_barrier(); FENCE;
        // ---- ph3: (ks1, mg1) ----
        READ_A(1, 1);
        if (u < 7) { STAGE_B(u + 1, 1); VMCNT(2); }
        __builtin_amdgcn_s_barrier(); FENCE;
        MFMAC(1);
        __builtin_amdgcn_s_barrier(); FENCE;
    }
#undef STAGE_A
#undef STAGE_B
#undef READ_A
#undef READ_B
#undef MFMAC

    // ---- epilogue: per-row sum(exp(logit)) / sum(logit), shfl over l15 ----
    __syncthreads();
    float* redE = (float*)lds;            // [256][4] f32 = 4KB
    float* redL = (float*)(lds + 2048);   // next 4KB

#pragma unroll
    for (int m = 0; m < 8; ++m) {
        float pe[4] = {0.f, 0.f, 0.f, 0.f}, pl[4] = {0.f, 0.f, 0.f, 0.f};
#pragma unroll
        for (int n = 0; n < 4; ++n) {
            int cc = cbase + wn * 64 + n * 16 + l15;
            if (cc < KC) {
                float bb2 = bias[cc];
#pragma unroll
                for (int rr = 0; rr < 4; ++rr) {
                    float lg = acc[m][n][rr] + bb2;
                    pe[rr] += __expf(lg);
                    pl[rr] += lg;
                }
            }
        }
#pragma unroll
        for (int rr = 0; rr < 4; ++rr) {
#pragma unroll
            for (int o = 1; o < 16; o <<= 1) {
                pe[rr] += __shfl_xor(pe[rr], o);
                pl[rr] += __shfl_xor(pl[rr], o);
            }
            if (l15 == 0) {
                int rowl = wm * 128 + m * 16 + q * 4 + rr;
                redE[rowl * 4 + wn] = pe[rr];
                redL[rowl * 4 + wn] = pl[rr];
            }
        }
    }
    __syncthreads();
    if (tid < 256) {
        float se = redE[tid * 4] + redE[tid * 4 + 1] + redE[tid * 4 + 2] + redE[tid * 4 + 3];
        float sl = redL[tid * 4] + redL[tid * 4 + 1] + redL[tid * 4 + 2] + redL[tid * 4 + 3];
        atomicAdd(&sumexp[rowbase + tid], se);
        atomicAdd(&sumlogit[rowbase + tid], sl);
    }
}

// ---------------- final combine ----------------
__global__ __launch_bounds__(1024) void final_kernel(const float* __restrict__ ws,
                                                     float* __restrict__ out) {
    const float* sumexp = ws;
    const float* sumlogit = ws + B;
    const float* t = ws + 2 * B;
    const float* tw = ws + 3 * B;
    int i = threadIdx.x;
    float lse = logf(sumexp[i]);
    float ce = lse - (1.f - EPSSM) * t[i] - (EPSSM / (float)KC) * sumlogit[i];
    float v = ce + tw[i];   // WEIGHT_T = WEIGHT_X = 1
    for (int o = 32; o >= 1; o >>= 1) v += __shfl_xor(v, o);
    __shared__ float red[16];
    int wid = threadIdx.x >> 6, lane = threadIdx.x & 63;
    if (lane == 0) red[wid] = v;
    __syncthreads();
    if (threadIdx.x == 0) {
        float s = 0.f;
#pragma unroll
        for (int w = 0; w < 16; ++w) s += red[w];
        out[0] = s / (float)B;
    }
}

extern "C" void kernel_launch(void* const* d_in, const int* in_sizes, int n_in,
                              void* d_out, int out_size, void* d_ws, size_t ws_size,
                              hipStream_t stream) {
    const float* x = (const float*)d_in[0];
    const float* W = (const float*)d_in[1];
    const float* bias = (const float*)d_in[2];
    const int* labels = (const int*)d_in[3];
    float* out = (float*)d_out;
    float* ws = (float*)d_ws;
    // ws: [0,16KB) stats {sumexp,sumlogit,t,tw}; xp bf16 1MB at +16KB; wp bf16 ~102.5MB after.

    unsigned short* xp = (unsigned short*)((char*)d_ws + 16384);
    unsigned short* wp = xp + (size_t)B * D;   // 391*256*512 bf16

    init_ws<<<(2 * B + 255) / 256, 256, 0, stream>>>(ws);
    triplet_kernel<<<B / 8, 256, 0, stream>>>(x, labels, ws + 3 * B);
    tlabel_kernel<<<B / 4, 256, 0, stream>>>(x, W, bias, labels, ws + 2 * B);
    pack_x<<<256, 256, 0, stream>>>(x, xp);
    pack_w<<<(KC * 64) / 256, 256, 0, stream>>>(W, wp);
    ce_gemm_p<<<8 * 4 * 49, 512, 131072, stream>>>(xp, wp, bias, ws, ws + B);
    final_kernel<<<1, 1024, 0, stream>>>(ws, out);
}